// Round 2
// baseline (255.160 us; speedup 1.0000x reference)
//
#include <hip/hip_runtime.h>

#define N_NODES 50000
#define N_EDGES 800000
#define D 128
#define NB 392            // partition chunk blocks (full CU coverage)
#define CHUNK 2048        // edges per chunk (392*2048 = 802816 >= 800000)
#define NBKT 391          // buckets = dst>>7 (128 nodes each)
#define LHM (NBKT * NB)   // hist matrix length 153272
#define NSB ((LHM + 255) / 256)   // 599
#define GB ((N_NODES + 127) / 128)   // 391 gemm tiles
#define AGB 782           // aggr blocks: 782*64 = 50048 node slots
#define NBIN 128          // degree bins for load-balance sort
#define BPAD 32           // pad bins to separate 128B lines (atomic contention)

typedef unsigned int uint32;
typedef unsigned short ushort;
typedef __attribute__((ext_vector_type(8))) short s8v;   // 8 x bf16 bits
typedef __attribute__((ext_vector_type(4))) float f4v;   // MFMA accumulator

__device__ __forceinline__ ushort f2bf(float f) {   // RNE bf16
    unsigned u = __float_as_uint(f);
    u += 0x7FFFu + ((u >> 16) & 1u);
    return (ushort)(u >> 16);
}
__device__ __forceinline__ float bf_lo(uint32 u) { return __uint_as_float(u << 16); }
__device__ __forceinline__ float bf_hi(uint32 u) { return __uint_as_float(u & 0xFFFF0000u); }

// ---- block-wide inclusive scan helper (256 threads = 4 waves) ----
__device__ __forceinline__ int block_incl_scan(int v, int t) {
    int lane = t & 63, wv = t >> 6;
    int incl = v;
    #pragma unroll
    for (int off = 1; off < 64; off <<= 1) {
        int u = __shfl_up(incl, off, 64);
        if (lane >= off) incl += u;
    }
    __shared__ int wsums[4];
    if (lane == 63) wsums[wv] = incl;
    __syncthreads();
    int add = 0;
    if (wv > 0) add += wsums[0];
    if (wv > 1) add += wsums[1];
    if (wv > 2) add += wsums[2];
    return incl + add;
}

// ---- K1: per-chunk bucket histogram (private slots, NO global atomics) + wprep ----
__global__ __launch_bounds__(256) void phaseA_kernel(const int* __restrict__ dst,
                                                     int* __restrict__ histM,
                                                     const float* __restrict__ W1,
                                                     const float* __restrict__ W2,
                                                     ushort* __restrict__ W1t,
                                                     ushort* __restrict__ W2t,
                                                     int* __restrict__ dhist) {
    int t = threadIdx.x, blk = blockIdx.x;
    if (blk == NB + 2) {                  // zero padded degree histogram
        for (int i = t; i < NBIN * BPAD; i += 256) dhist[i] = 0;
        return;
    }
    if (blk >= NB) {                      // 2 tail blocks: weight transpose+cvt
        const float* W = (blk - NB) ? W2 : W1;
        ushort* Wt = (blk - NB) ? W2t : W1t;
        #pragma unroll
        for (int it = 0; it < 16; it++) {
            int fid = t + it * 256;       // float4 id 0..4095
            int k = fid >> 5;
            int n0 = (fid & 31) * 4;
            float4 w = ((const float4*)W)[fid];
            Wt[(n0 + 0) * D + k] = f2bf(w.x);
            Wt[(n0 + 1) * D + k] = f2bf(w.y);
            Wt[(n0 + 2) * D + k] = f2bf(w.z);
            Wt[(n0 + 3) * D + k] = f2bf(w.w);
        }
        return;
    }
    __shared__ int lc[NBKT];
    for (int i = t; i < NBKT; i += 256) lc[i] = 0;
    __syncthreads();
    int e0 = blk * CHUNK;
    #pragma unroll
    for (int j = 0; j < 8; j++) {
        int e = e0 + t + j * 256;
        if (e < N_EDGES) atomicAdd(&lc[dst[e] >> 7], 1);
    }
    __syncthreads();
    for (int i = t; i < NBKT; i += 256)
        histM[i * NB + blk] = lc[i];      // bucket-major, block-minor (private slot)
}

// ---- scan pass 1: block-local exclusive + block sums ----
__global__ __launch_bounds__(256) void scan1g(const int* __restrict__ in,
                                              int* __restrict__ out,
                                              int* __restrict__ bsum) {
    int t = threadIdx.x, blk = blockIdx.x;
    int i = blk * 256 + t;
    int v = (i < LHM) ? in[i] : 0;
    int incl = block_incl_scan(v, t);
    if (i < LHM) out[i] = incl - v;
    if (t == 255) bsum[blk] = incl;
}

// ---- scan pass 2 (merged): each block reduces its bsum-prefix, adds to its tile ----
__global__ __launch_bounds__(256) void scan23g(int* __restrict__ out,
                                               const int* __restrict__ bsum) {
    int t = threadIdx.x, blk = blockIdx.x;
    int local = 0;
    for (int i = t; i < blk; i += 256) local += bsum[i];
    int lane = t & 63, wv = t >> 6;
    #pragma unroll
    for (int off = 32; off > 0; off >>= 1) local += __shfl_down(local, off, 64);
    __shared__ int ws[4];
    if (lane == 0) ws[wv] = local;
    __syncthreads();
    int boff = ws[0] + ws[1] + ws[2] + ws[3];
    int i = blk * 256 + t;
    if (i < LHM) out[i] += boff;
}

// ---- K3: phaseC — partition edges into bucket-major order (no global atomics) ----
__global__ __launch_bounds__(256) void phaseC_kernel(const int* __restrict__ src,
                                                     const int* __restrict__ dst,
                                                     const int* __restrict__ base,
                                                     uint32* __restrict__ edgeTmp) {
    __shared__ int cur[NBKT];
    int t = threadIdx.x, blk = blockIdx.x;
    for (int i = t; i < NBKT; i += 256) cur[i] = base[i * NB + blk];
    __syncthreads();
    int e0 = blk * CHUNK;
    #pragma unroll
    for (int j = 0; j < 8; j++) {
        int e = e0 + t + j * 256;
        if (e < N_EDGES) {
            uint32 s = (uint32)src[e], d = (uint32)dst[e];
            int p = atomicAdd(&cur[d >> 7], 1);      // LDS atomic
            edgeTmp[p] = (s << 16) | d;              // both < 65536
        }
    }
}

// ---- K4: per-bucket (128 nodes) counting sort + rowstart + dis ----
__global__ __launch_bounds__(256) void phaseD_kernel(const uint32* __restrict__ edgeTmp,
                                                     const int* __restrict__ base,
                                                     int* __restrict__ rowstart,
                                                     float* __restrict__ dis,
                                                     ushort* __restrict__ e16) {
    __shared__ int cnt[128];
    __shared__ int cur[128];
    int t = threadIdx.x, b = blockIdx.x;
    int beg = base[b * NB];
    int end = (b == NBKT - 1) ? N_EDGES : base[(b + 1) * NB];
    if (t < 128) cnt[t] = 0;
    __syncthreads();
    for (int p = beg + t; p < end; p += 256)
        atomicAdd(&cnt[edgeTmp[p] & 127], 1);
    __syncthreads();
    int c = (t < 128) ? cnt[t] : 0;
    int incl = block_incl_scan(c, t);
    int excl = incl - c;
    int node = b * 128 + t;
    if (t < 128) {
        if (node <= N_NODES) rowstart[node] = beg + excl;
        if (node < N_NODES) dis[node] = rsqrtf((float)(c + 1));
        cur[t] = excl;
    }
    __syncthreads();
    for (int p = beg + t; p < end; p += 256) {
        uint32 u = edgeTmp[p];
        int r = atomicAdd(&cur[u & 127], 1);            // LDS atomic
        e16[beg + r] = (ushort)(u >> 16);
    }
}

// ---- degree histogram (two-level: LDS then padded global bins) ----
__global__ __launch_bounds__(256) void histdeg_kernel(const int* __restrict__ rowstart,
                                                      int* __restrict__ dhist) {
    __shared__ int dh[NBIN];
    int t = threadIdx.x;
    if (t < NBIN) dh[t] = 0;
    __syncthreads();
    int n = blockIdx.x * 256 + t;
    if (n < N_NODES) {
        int deg = rowstart[n + 1] - rowstart[n];
        atomicAdd(&dh[deg > NBIN - 1 ? NBIN - 1 : deg], 1);
    }
    __syncthreads();
    if (t < NBIN && dh[t] > 0) atomicAdd(&dhist[t * BPAD], dh[t]);
}

// ---- exclusive scan of 128 degree bins (1 block) ----
__global__ __launch_bounds__(128) void scandeg_kernel(const int* __restrict__ dhist,
                                                      int* __restrict__ dcur) {
    __shared__ int s[NBIN];
    int t = threadIdx.x;
    int v0 = dhist[t * BPAD];
    s[t] = v0;
    __syncthreads();
    for (int off = 1; off < NBIN; off <<= 1) {
        int v = (t >= off) ? s[t - off] : 0;
        __syncthreads();
        s[t] += v;
        __syncthreads();
    }
    dcur[t * BPAD] = s[t] - v0;   // exclusive prefix
}

// ---- build degree-balanced node permutation ----
// rank r (by degree) -> chunk j=r/16 of 16 equal-degree nodes -> wave (j/AGB) of
// block (j%AGB). Waves are degree-uniform (no tail divergence); blocks mix degrees
// (balanced lifetimes so the quarter loop stays temporally aligned across the grid).
__global__ __launch_bounds__(256) void permbuild_kernel(const int* __restrict__ rowstart,
                                                        int* __restrict__ dcur,
                                                        int* __restrict__ perm) {
    __shared__ int bh[NBIN];
    __shared__ int bbase[NBIN];
    int t = threadIdx.x;
    if (t < NBIN) bh[t] = 0;
    __syncthreads();
    int n = blockIdx.x * 256 + t;
    int bin = -1, myloc = 0;
    if (n < N_NODES) {
        int deg = rowstart[n + 1] - rowstart[n];
        bin = deg > NBIN - 1 ? NBIN - 1 : deg;
        myloc = atomicAdd(&bh[bin], 1);              // local rank within bin
    }
    __syncthreads();
    if (t < NBIN && bh[t] > 0) bbase[t] = atomicAdd(&dcur[t * BPAD], bh[t]);
    __syncthreads();
    if (n < N_NODES) {
        int r = bbase[bin] + myloc;
        int j = r >> 4, i = r & 15;
        int wv = j / AGB, b = j - wv * AGB;
        perm[b * 64 + wv * 16 + i] = n;
    }
}

// ---- Hb = bf16(dis[r] * (X @ W)) via MFMA 16x16x32 bf16, dis folded ----
template<bool BF16IN>
__global__ __launch_bounds__(256) void gemm_mfma(const void* __restrict__ Xv,
                                                 const ushort* __restrict__ Wt,
                                                 const float* __restrict__ dis,
                                                 ushort* __restrict__ Hb) {
    __shared__ ushort Cs[128 * 136];
    int t = threadIdx.x;
    int wv = t >> 6, lane = t & 63;
    int q = lane >> 4, m = lane & 15;
    int rbase = blockIdx.x * 128 + wv * 32;
    f4v zero = {0.f, 0.f, 0.f, 0.f};
    f4v acc[2][8];
    #pragma unroll
    for (int mt = 0; mt < 2; mt++)
        #pragma unroll
        for (int n = 0; n < 8; n++) acc[mt][n] = zero;

    #pragma unroll
    for (int kt = 0; kt < 4; kt++) {
        int k0 = kt * 32 + q * 8;
        s8v a[2];
        #pragma unroll
        for (int mt = 0; mt < 2; mt++) {
            int row = rbase + mt * 16 + m;
            if (row >= N_NODES) row = N_NODES - 1;
            if (BF16IN) {
                const ushort* xp = (const ushort*)Xv + (size_t)row * D + k0;
                a[mt] = *(const s8v*)xp;                       // 16B load
            } else {
                const float* xp = (const float*)Xv + (size_t)row * D + k0;
                float4 u0 = *(const float4*)xp;
                float4 u1 = *(const float4*)(xp + 4);
                s8v av;
                av[0] = (short)f2bf(u0.x); av[1] = (short)f2bf(u0.y);
                av[2] = (short)f2bf(u0.z); av[3] = (short)f2bf(u0.w);
                av[4] = (short)f2bf(u1.x); av[5] = (short)f2bf(u1.y);
                av[6] = (short)f2bf(u1.z); av[7] = (short)f2bf(u1.w);
                a[mt] = av;
            }
        }
        #pragma unroll
        for (int n = 0; n < 8; n++) {
            s8v b = *(const s8v*)(Wt + (size_t)(n * 16 + m) * D + k0);
            acc[0][n] = __builtin_amdgcn_mfma_f32_16x16x32_bf16(a[0], b, acc[0][n], 0, 0, 0);
            acc[1][n] = __builtin_amdgcn_mfma_f32_16x16x32_bf16(a[1], b, acc[1][n], 0, 0, 0);
        }
    }
    float disv[2][4];
    #pragma unroll
    for (int mt = 0; mt < 2; mt++)
        #pragma unroll
        for (int r = 0; r < 4; r++) {
            int row = rbase + mt * 16 + q * 4 + r;
            if (row >= N_NODES) row = N_NODES - 1;
            disv[mt][r] = dis[row];
        }
    #pragma unroll
    for (int mt = 0; mt < 2; mt++)
        #pragma unroll
        for (int n = 0; n < 8; n++)
            #pragma unroll
            for (int r = 0; r < 4; r++) {
                int row = wv * 32 + mt * 16 + q * 4 + r;
                Cs[row * 136 + n * 16 + m] = f2bf(acc[mt][n][r] * disv[mt][r]);
            }
    __syncthreads();
    int gbase = blockIdx.x * 128;
    #pragma unroll
    for (int it = 0; it < 8; it++) {
        int cid = t + it * 256;
        int row = cid >> 4, off = (cid & 15) * 8;
        int grow = gbase + row;
        if (grow < N_NODES) {
            s8v v = *(const s8v*)(Cs + row * 136 + off);
            *(s8v*)(Hb + (size_t)grow * D + off) = v;
        }
    }
}

// ---- aggregate: out = relu(dis[n]*(Hb[n]+sum Hb[src])+b), quartered channels ----
// 4 lanes/node (16B each = 32 ch/quarter); 4 sequential quarters per block so the
// active gather table is 3.2 MiB (fits 4 MiB per-XCD L2: ~16x re-gathers hit L2).
// Node order = degree-balanced perm: every 16-node wave-group has uniform degree.
__device__ __forceinline__ void acc8(float* a, uint4 v) {
    a[0] += bf_lo(v.x); a[1] += bf_hi(v.x);
    a[2] += bf_lo(v.y); a[3] += bf_hi(v.y);
    a[4] += bf_lo(v.z); a[5] += bf_hi(v.z);
    a[6] += bf_lo(v.w); a[7] += bf_hi(v.w);
}

template<bool BF16OUT>
__global__ __launch_bounds__(256) void aggr_kernel(const uint4* __restrict__ Hb4,
                                                   const float* __restrict__ dis,
                                                   const int* __restrict__ rowstart,
                                                   const ushort* __restrict__ e16,
                                                   const int* __restrict__ perm,
                                                   const float* __restrict__ bias,
                                                   void* __restrict__ Hout) {
    int t = threadIdx.x;
    int li = t & 3;                        // uint4 lane within quarter
    int wv = t >> 6;
    int i16 = (t >> 2) & 15;               // node-group within wave
    int b = blockIdx.x;
    int r = (wv * AGB + b) * 16 + i16;     // degree-sorted rank of this slot
    bool valid = (r < N_NODES);
    int n = 0; float dn = 0.f; int beg = 0, end = 0;
    if (valid) {
        n = perm[b * 64 + wv * 16 + i16];
        dn = dis[n];
        beg = rowstart[n]; end = rowstart[n + 1];
    }
    const float4* b4 = (const float4*)bias;
    #pragma unroll 1
    for (int qtr = 0; qtr < 4; qtr++) {
        if (valid) {
            int ci = qtr * 4 + li;         // uint4 index within row (0..15)
            float a[8];
            {
                uint4 sv = Hb4[(size_t)n * 16 + ci];   // self term (dis folded)
                a[0] = bf_lo(sv.x); a[1] = bf_hi(sv.x);
                a[2] = bf_lo(sv.y); a[3] = bf_hi(sv.y);
                a[4] = bf_lo(sv.z); a[5] = bf_hi(sv.z);
                a[6] = bf_lo(sv.w); a[7] = bf_hi(sv.w);
            }
            int p = beg;
            for (; p + 7 < end; p += 8) {  // 8 outstanding 16B gathers per lane
                int s[8];
                #pragma unroll
                for (int j = 0; j < 8; j++) s[j] = e16[p + j];
                uint4 v[8];
                #pragma unroll
                for (int j = 0; j < 8; j++) v[j] = Hb4[(size_t)s[j] * 16 + ci];
                #pragma unroll
                for (int j = 0; j < 8; j++) acc8(a, v[j]);
            }
            for (; p + 3 < end; p += 4) {
                int s0 = e16[p + 0], s1 = e16[p + 1], s2 = e16[p + 2], s3 = e16[p + 3];
                uint4 v0 = Hb4[(size_t)s0 * 16 + ci];
                uint4 v1 = Hb4[(size_t)s1 * 16 + ci];
                uint4 v2 = Hb4[(size_t)s2 * 16 + ci];
                uint4 v3 = Hb4[(size_t)s3 * 16 + ci];
                acc8(a, v0); acc8(a, v1); acc8(a, v2); acc8(a, v3);
            }
            for (; p < end; p++) {
                uint4 v0 = Hb4[(size_t)e16[p] * 16 + ci];
                acc8(a, v0);
            }
            float4 bb0 = b4[ci * 2], bb1 = b4[ci * 2 + 1];
            float r0 = fmaxf(fmaf(dn, a[0], bb0.x), 0.f);
            float r1 = fmaxf(fmaf(dn, a[1], bb0.y), 0.f);
            float r2 = fmaxf(fmaf(dn, a[2], bb0.z), 0.f);
            float r3 = fmaxf(fmaf(dn, a[3], bb0.w), 0.f);
            float r4 = fmaxf(fmaf(dn, a[4], bb1.x), 0.f);
            float r5 = fmaxf(fmaf(dn, a[5], bb1.y), 0.f);
            float r6 = fmaxf(fmaf(dn, a[6], bb1.z), 0.f);
            float r7 = fmaxf(fmaf(dn, a[7], bb1.w), 0.f);
            if (BF16OUT) {
                uint4 o;
                o.x = (uint32)f2bf(r0) | ((uint32)f2bf(r1) << 16);
                o.y = (uint32)f2bf(r2) | ((uint32)f2bf(r3) << 16);
                o.z = (uint32)f2bf(r4) | ((uint32)f2bf(r5) << 16);
                o.w = (uint32)f2bf(r6) | ((uint32)f2bf(r7) << 16);
                ((uint4*)Hout)[(size_t)n * 16 + ci] = o;
            } else {
                float4* H4 = (float4*)Hout;
                float4 o0; o0.x = r0; o0.y = r1; o0.z = r2; o0.w = r3;
                float4 o1; o1.x = r4; o1.y = r5; o1.z = r6; o1.w = r7;
                H4[(size_t)n * 32 + ci * 2]     = o0;
                H4[(size_t)n * 32 + ci * 2 + 1] = o1;
            }
        }
    }
}

extern "C" void kernel_launch(void* const* d_in, const int* in_sizes, int n_in,
                              void* d_out, int out_size, void* d_ws, size_t ws_size,
                              hipStream_t stream) {
    const float* x  = (const float*)d_in[0];
    const int*   ei = (const int*)d_in[1];   // int32 per harness contract
    const float* W1 = (const float*)d_in[2];
    const float* b1 = (const float*)d_in[3];
    const float* W2 = (const float*)d_in[4];
    const float* b2 = (const float*)d_in[5];
    float* out = (float*)d_out;

    char* ws = (char*)d_ws;
    size_t off = 0;
    auto alloc = [&](size_t bytes) -> void* {
        void* p = ws + off;
        off += (bytes + 255) & ~(size_t)255;
        return p;
    };
    int*    histM    = (int*)alloc((size_t)LHM * 4);
    int*    base     = (int*)alloc((size_t)LHM * 4);
    int*    bsum     = (int*)alloc((size_t)NSB * 4);
    int*    rowstart = (int*)alloc((size_t)(N_NODES + 1) * 4);
    float*  dis      = (float*)alloc((size_t)N_NODES * 4);
    uint32* edgeTmp  = (uint32*)alloc((size_t)N_EDGES * 4);
    ushort* e16      = (ushort*)alloc((size_t)N_EDGES * 2);
    ushort* Hb       = (ushort*)alloc((size_t)N_NODES * D * 2);
    ushort* HO1      = (ushort*)alloc((size_t)N_NODES * D * 2);   // layer-1 out bf16
    ushort* W1t      = (ushort*)alloc((size_t)D * D * 2);
    ushort* W2t      = (ushort*)alloc((size_t)D * D * 2);
    int*    dhist    = (int*)alloc((size_t)NBIN * BPAD * 4);
    int*    dcur     = (int*)alloc((size_t)NBIN * BPAD * 4);
    int*    perm     = (int*)alloc((size_t)AGB * 64 * 4);

    const int* src = ei;             // edge_index[0]
    const int* dst = ei + N_EDGES;   // edge_index[1]

    phaseA_kernel<<<NB + 3, 256, 0, stream>>>(dst, histM, W1, W2, W1t, W2t, dhist);
    scan1g<<<NSB, 256, 0, stream>>>(histM, base, bsum);
    scan23g<<<NSB, 256, 0, stream>>>(base, bsum);
    phaseC_kernel<<<NB, 256, 0, stream>>>(src, dst, base, edgeTmp);
    phaseD_kernel<<<NBKT, 256, 0, stream>>>(edgeTmp, base, rowstart, dis, e16);
    histdeg_kernel<<<(N_NODES + 255) / 256, 256, 0, stream>>>(rowstart, dhist);
    scandeg_kernel<<<1, 128, 0, stream>>>(dhist, dcur);
    permbuild_kernel<<<(N_NODES + 255) / 256, 256, 0, stream>>>(rowstart, dcur, perm);

    gemm_mfma<false><<<GB, 256, 0, stream>>>(x, W1t, dis, Hb);
    aggr_kernel<true><<<AGB, 256, 0, stream>>>((const uint4*)Hb, dis, rowstart,
                                               e16, perm, b1, HO1);
    gemm_mfma<true><<<GB, 256, 0, stream>>>(HO1, W2t, dis, Hb);
    aggr_kernel<false><<<AGB, 256, 0, stream>>>((const uint4*)Hb, dis, rowstart,
                                                e16, perm, b2, out);
}

// Round 3
// 217.442 us; speedup vs baseline: 1.1735x; 1.1735x over previous
//
#include <hip/hip_runtime.h>

#define N_NODES 50000
#define N_EDGES 800000
#define D 128
#define NB 392            // partition chunk blocks (full CU coverage)
#define CHUNK 2048        // edges per chunk (392*2048 = 802816 >= 800000)
#define NBKT 391          // buckets = dst>>7 (128 nodes each)
#define LHM (NBKT * NB)   // hist matrix length 153272
#define NSB ((LHM + 255) / 256)   // 599
#define GB ((N_NODES + 127) / 128)   // 391 gemm tiles
#define PB 3125           // aggr blocks: 3125*16 = 50000 nodes, 4 waves/block
#define NBIN 128          // degree bins for load-balance sort
#define BPAD 32           // pad bins to separate 128B lines (atomic contention)

typedef unsigned int uint32;
typedef unsigned short ushort;
typedef __attribute__((ext_vector_type(8))) short s8v;   // 8 x bf16 bits
typedef __attribute__((ext_vector_type(4))) float f4v;   // MFMA accumulator

__device__ __forceinline__ ushort f2bf(float f) {   // RNE bf16
    unsigned u = __float_as_uint(f);
    u += 0x7FFFu + ((u >> 16) & 1u);
    return (ushort)(u >> 16);
}
__device__ __forceinline__ float bf_lo(uint32 u) { return __uint_as_float(u << 16); }
__device__ __forceinline__ float bf_hi(uint32 u) { return __uint_as_float(u & 0xFFFF0000u); }

// ---- block-wide inclusive scan helper (256 threads = 4 waves) ----
__device__ __forceinline__ int block_incl_scan(int v, int t) {
    int lane = t & 63, wv = t >> 6;
    int incl = v;
    #pragma unroll
    for (int off = 1; off < 64; off <<= 1) {
        int u = __shfl_up(incl, off, 64);
        if (lane >= off) incl += u;
    }
    __shared__ int wsums[4];
    if (lane == 63) wsums[wv] = incl;
    __syncthreads();
    int add = 0;
    if (wv > 0) add += wsums[0];
    if (wv > 1) add += wsums[1];
    if (wv > 2) add += wsums[2];
    return incl + add;
}

// ---- K1: per-chunk bucket histogram (private slots, NO global atomics) + wprep ----
__global__ __launch_bounds__(256) void phaseA_kernel(const int* __restrict__ dst,
                                                     int* __restrict__ histM,
                                                     const float* __restrict__ W1,
                                                     const float* __restrict__ W2,
                                                     ushort* __restrict__ W1t,
                                                     ushort* __restrict__ W2t,
                                                     int* __restrict__ dhist) {
    int t = threadIdx.x, blk = blockIdx.x;
    if (blk == NB + 2) {                  // zero padded degree histogram
        for (int i = t; i < NBIN * BPAD; i += 256) dhist[i] = 0;
        return;
    }
    if (blk >= NB) {                      // 2 tail blocks: weight transpose+cvt
        const float* W = (blk - NB) ? W2 : W1;
        ushort* Wt = (blk - NB) ? W2t : W1t;
        #pragma unroll
        for (int it = 0; it < 16; it++) {
            int fid = t + it * 256;       // float4 id 0..4095
            int k = fid >> 5;
            int n0 = (fid & 31) * 4;
            float4 w = ((const float4*)W)[fid];
            Wt[(n0 + 0) * D + k] = f2bf(w.x);
            Wt[(n0 + 1) * D + k] = f2bf(w.y);
            Wt[(n0 + 2) * D + k] = f2bf(w.z);
            Wt[(n0 + 3) * D + k] = f2bf(w.w);
        }
        return;
    }
    __shared__ int lc[NBKT];
    for (int i = t; i < NBKT; i += 256) lc[i] = 0;
    __syncthreads();
    int e0 = blk * CHUNK;
    #pragma unroll
    for (int j = 0; j < 8; j++) {
        int e = e0 + t + j * 256;
        if (e < N_EDGES) atomicAdd(&lc[dst[e] >> 7], 1);
    }
    __syncthreads();
    for (int i = t; i < NBKT; i += 256)
        histM[i * NB + blk] = lc[i];      // bucket-major, block-minor (private slot)
}

// ---- scan pass 1: block-local exclusive + block sums ----
__global__ __launch_bounds__(256) void scan1g(const int* __restrict__ in,
                                              int* __restrict__ out,
                                              int* __restrict__ bsum) {
    int t = threadIdx.x, blk = blockIdx.x;
    int i = blk * 256 + t;
    int v = (i < LHM) ? in[i] : 0;
    int incl = block_incl_scan(v, t);
    if (i < LHM) out[i] = incl - v;
    if (t == 255) bsum[blk] = incl;
}

// ---- scan pass 2 (merged): each block reduces its bsum-prefix, adds to its tile ----
__global__ __launch_bounds__(256) void scan23g(int* __restrict__ out,
                                               const int* __restrict__ bsum) {
    int t = threadIdx.x, blk = blockIdx.x;
    int local = 0;
    for (int i = t; i < blk; i += 256) local += bsum[i];
    int lane = t & 63, wv = t >> 6;
    #pragma unroll
    for (int off = 32; off > 0; off >>= 1) local += __shfl_down(local, off, 64);
    __shared__ int ws[4];
    if (lane == 0) ws[wv] = local;
    __syncthreads();
    int boff = ws[0] + ws[1] + ws[2] + ws[3];
    int i = blk * 256 + t;
    if (i < LHM) out[i] += boff;
}

// ---- K3: phaseC — partition edges into bucket-major order (no global atomics) ----
__global__ __launch_bounds__(256) void phaseC_kernel(const int* __restrict__ src,
                                                     const int* __restrict__ dst,
                                                     const int* __restrict__ base,
                                                     uint32* __restrict__ edgeTmp) {
    __shared__ int cur[NBKT];
    int t = threadIdx.x, blk = blockIdx.x;
    for (int i = t; i < NBKT; i += 256) cur[i] = base[i * NB + blk];
    __syncthreads();
    int e0 = blk * CHUNK;
    #pragma unroll
    for (int j = 0; j < 8; j++) {
        int e = e0 + t + j * 256;
        if (e < N_EDGES) {
            uint32 s = (uint32)src[e], d = (uint32)dst[e];
            int p = atomicAdd(&cur[d >> 7], 1);      // LDS atomic
            edgeTmp[p] = (s << 16) | d;              // both < 65536
        }
    }
}

// ---- K4: per-bucket (128 nodes) counting sort + rowstart + dis + degree hist ----
__global__ __launch_bounds__(256) void phaseD_kernel(const uint32* __restrict__ edgeTmp,
                                                     const int* __restrict__ base,
                                                     int* __restrict__ rowstart,
                                                     float* __restrict__ dis,
                                                     ushort* __restrict__ e16,
                                                     int* __restrict__ dhist) {
    __shared__ int cnt[128];
    __shared__ int cur[128];
    __shared__ int dh[NBIN];
    int t = threadIdx.x, b = blockIdx.x;
    int beg = base[b * NB];
    int end = (b == NBKT - 1) ? N_EDGES : base[(b + 1) * NB];
    if (t < 128) cnt[t] = 0; else dh[t - 128] = 0;   // NBIN==128
    __syncthreads();
    for (int p = beg + t; p < end; p += 256)
        atomicAdd(&cnt[edgeTmp[p] & 127], 1);
    __syncthreads();
    int c = (t < 128) ? cnt[t] : 0;
    int node = b * 128 + t;
    if (t < 128 && node < N_NODES)
        atomicAdd(&dh[c > NBIN - 1 ? NBIN - 1 : c], 1);   // fused degree histogram
    int incl = block_incl_scan(c, t);    // contains __syncthreads (orders dh adds)
    int excl = incl - c;
    if (t < 128) {
        if (node <= N_NODES) rowstart[node] = beg + excl;
        if (node < N_NODES) dis[node] = rsqrtf((float)(c + 1));
        cur[t] = excl;
    }
    __syncthreads();
    if (t < 128 && dh[t] > 0) atomicAdd(&dhist[t * BPAD], dh[t]);
    for (int p = beg + t; p < end; p += 256) {
        uint32 u = edgeTmp[p];
        int r = atomicAdd(&cur[u & 127], 1);            // LDS atomic
        e16[beg + r] = (ushort)(u >> 16);
    }
}

// ---- exclusive scan of 128 degree bins (1 block) ----
__global__ __launch_bounds__(128) void scandeg_kernel(const int* __restrict__ dhist,
                                                      int* __restrict__ dcur) {
    __shared__ int s[NBIN];
    int t = threadIdx.x;
    int v0 = dhist[t * BPAD];
    s[t] = v0;
    __syncthreads();
    for (int off = 1; off < NBIN; off <<= 1) {
        int v = (t >= off) ? s[t - off] : 0;
        __syncthreads();
        s[t] += v;
        __syncthreads();
    }
    dcur[t * BPAD] = s[t] - v0;   // exclusive prefix
}

// ---- build degree-balanced node permutation ----
// rank r (by degree) -> wave-chunk j=r/4 of 4 equal-degree nodes -> wave (j/PB) of
// block (j%PB). Waves are degree-uniform (no gather-tail divergence); each block
// gets 4 waves strided across the sorted order (balanced block lifetimes).
__global__ __launch_bounds__(256) void permbuild_kernel(const int* __restrict__ rowstart,
                                                        int* __restrict__ dcur,
                                                        int* __restrict__ perm) {
    __shared__ int bh[NBIN];
    __shared__ int bbase[NBIN];
    int t = threadIdx.x;
    if (t < NBIN) bh[t] = 0;
    __syncthreads();
    int n = blockIdx.x * 256 + t;
    int bin = -1, myloc = 0;
    if (n < N_NODES) {
        int deg = rowstart[n + 1] - rowstart[n];
        bin = deg > NBIN - 1 ? NBIN - 1 : deg;
        myloc = atomicAdd(&bh[bin], 1);              // local rank within bin
    }
    __syncthreads();
    if (t < NBIN && bh[t] > 0) bbase[t] = atomicAdd(&dcur[t * BPAD], bh[t]);
    __syncthreads();
    if (n < N_NODES) {
        int r = bbase[bin] + myloc;                  // global degree rank 0..49999
        int j = r >> 2, i = r & 3;                   // wave-chunk, lane-node
        int wv = j / PB, b = j - wv * PB;            // wv in [0,4)
        perm[b * 16 + wv * 4 + i] = n;               // bijective: 3125*16 = 50000
    }
}

// ---- Hb = bf16(dis[r] * (X @ W)) via MFMA 16x16x32 bf16, dis folded ----
template<bool BF16IN>
__global__ __launch_bounds__(256) void gemm_mfma(const void* __restrict__ Xv,
                                                 const ushort* __restrict__ Wt,
                                                 const float* __restrict__ dis,
                                                 ushort* __restrict__ Hb) {
    __shared__ ushort Cs[128 * 136];
    int t = threadIdx.x;
    int wv = t >> 6, lane = t & 63;
    int q = lane >> 4, m = lane & 15;
    int rbase = blockIdx.x * 128 + wv * 32;
    f4v zero = {0.f, 0.f, 0.f, 0.f};
    f4v acc[2][8];
    #pragma unroll
    for (int mt = 0; mt < 2; mt++)
        #pragma unroll
        for (int n = 0; n < 8; n++) acc[mt][n] = zero;

    #pragma unroll
    for (int kt = 0; kt < 4; kt++) {
        int k0 = kt * 32 + q * 8;
        s8v a[2];
        #pragma unroll
        for (int mt = 0; mt < 2; mt++) {
            int row = rbase + mt * 16 + m;
            if (row >= N_NODES) row = N_NODES - 1;
            if (BF16IN) {
                const ushort* xp = (const ushort*)Xv + (size_t)row * D + k0;
                a[mt] = *(const s8v*)xp;                       // 16B load
            } else {
                const float* xp = (const float*)Xv + (size_t)row * D + k0;
                float4 u0 = *(const float4*)xp;
                float4 u1 = *(const float4*)(xp + 4);
                s8v av;
                av[0] = (short)f2bf(u0.x); av[1] = (short)f2bf(u0.y);
                av[2] = (short)f2bf(u0.z); av[3] = (short)f2bf(u0.w);
                av[4] = (short)f2bf(u1.x); av[5] = (short)f2bf(u1.y);
                av[6] = (short)f2bf(u1.z); av[7] = (short)f2bf(u1.w);
                a[mt] = av;
            }
        }
        #pragma unroll
        for (int n = 0; n < 8; n++) {
            s8v b = *(const s8v*)(Wt + (size_t)(n * 16 + m) * D + k0);
            acc[0][n] = __builtin_amdgcn_mfma_f32_16x16x32_bf16(a[0], b, acc[0][n], 0, 0, 0);
            acc[1][n] = __builtin_amdgcn_mfma_f32_16x16x32_bf16(a[1], b, acc[1][n], 0, 0, 0);
        }
    }
    float disv[2][4];
    #pragma unroll
    for (int mt = 0; mt < 2; mt++)
        #pragma unroll
        for (int r = 0; r < 4; r++) {
            int row = rbase + mt * 16 + q * 4 + r;
            if (row >= N_NODES) row = N_NODES - 1;
            disv[mt][r] = dis[row];
        }
    #pragma unroll
    for (int mt = 0; mt < 2; mt++)
        #pragma unroll
        for (int n = 0; n < 8; n++)
            #pragma unroll
            for (int r = 0; r < 4; r++) {
                int row = wv * 32 + mt * 16 + q * 4 + r;
                Cs[row * 136 + n * 16 + m] = f2bf(acc[mt][n][r] * disv[mt][r]);
            }
    __syncthreads();
    int gbase = blockIdx.x * 128;
    #pragma unroll
    for (int it = 0; it < 8; it++) {
        int cid = t + it * 256;
        int row = cid >> 4, off = (cid & 15) * 8;
        int grow = gbase + row;
        if (grow < N_NODES) {
            s8v v = *(const s8v*)(Cs + row * 136 + off);
            *(s8v*)(Hb + (size_t)grow * D + off) = v;
        }
    }
}

// ---- aggregate: out = relu(dis[n]*(Hb[n]+sum Hb[src])+b), 16 lanes/node ----
// Full-row gathers (256B/node, full cache-line utilization — quartering measured
// 2x WORSE: 64B requests halve line utilization, 4x request count, no L2-residency
// gain since each XCD L2 needs its own copy). Node order via degree-balanced perm:
// each wave's 4 nodes have equal degree -> no gather-loop tail divergence.
__device__ __forceinline__ void acc8(float* a, uint4 v) {
    a[0] += bf_lo(v.x); a[1] += bf_hi(v.x);
    a[2] += bf_lo(v.y); a[3] += bf_hi(v.y);
    a[4] += bf_lo(v.z); a[5] += bf_hi(v.z);
    a[6] += bf_lo(v.w); a[7] += bf_hi(v.w);
}

template<bool BF16OUT>
__global__ __launch_bounds__(256) void aggr_kernel(const uint4* __restrict__ Hb4,
                                                   const float* __restrict__ dis,
                                                   const int* __restrict__ rowstart,
                                                   const ushort* __restrict__ e16,
                                                   const int* __restrict__ perm,
                                                   const float* __restrict__ bias,
                                                   void* __restrict__ Hout) {
    int t = threadIdx.x;
    int li = t & 15;                       // lane in group: channels li*8..li*8+7
    int n = perm[blockIdx.x * 16 + (t >> 4)];   // degree-balanced slot -> node
    float dn = dis[n];
    float a[8];
    {
        uint4 sv = Hb4[(size_t)n * 16 + li];   // self term (dis[n] folded into Hb)
        a[0] = bf_lo(sv.x); a[1] = bf_hi(sv.x);
        a[2] = bf_lo(sv.y); a[3] = bf_hi(sv.y);
        a[4] = bf_lo(sv.z); a[5] = bf_hi(sv.z);
        a[6] = bf_lo(sv.w); a[7] = bf_hi(sv.w);
    }
    int beg = rowstart[n], end = rowstart[n + 1];
    int p = beg;
    for (; p + 7 < end; p += 8) {          // 8 outstanding 16B gathers per lane
        int s[8];
        #pragma unroll
        for (int j = 0; j < 8; j++) s[j] = e16[p + j];
        uint4 v[8];
        #pragma unroll
        for (int j = 0; j < 8; j++) v[j] = Hb4[(size_t)s[j] * 16 + li];
        #pragma unroll
        for (int j = 0; j < 8; j++) acc8(a, v[j]);
    }
    for (; p + 3 < end; p += 4) {
        int s0 = e16[p + 0], s1 = e16[p + 1], s2 = e16[p + 2], s3 = e16[p + 3];
        uint4 v0 = Hb4[(size_t)s0 * 16 + li];
        uint4 v1 = Hb4[(size_t)s1 * 16 + li];
        uint4 v2 = Hb4[(size_t)s2 * 16 + li];
        uint4 v3 = Hb4[(size_t)s3 * 16 + li];
        acc8(a, v0); acc8(a, v1); acc8(a, v2); acc8(a, v3);
    }
    for (; p < end; p++) {
        uint4 v0 = Hb4[(size_t)e16[p] * 16 + li];
        acc8(a, v0);
    }
    const float4* b4 = (const float4*)bias;
    float4 bb0 = b4[li * 2], bb1 = b4[li * 2 + 1];
    float r0 = fmaxf(fmaf(dn, a[0], bb0.x), 0.f);
    float r1 = fmaxf(fmaf(dn, a[1], bb0.y), 0.f);
    float r2 = fmaxf(fmaf(dn, a[2], bb0.z), 0.f);
    float r3 = fmaxf(fmaf(dn, a[3], bb0.w), 0.f);
    float r4 = fmaxf(fmaf(dn, a[4], bb1.x), 0.f);
    float r5 = fmaxf(fmaf(dn, a[5], bb1.y), 0.f);
    float r6 = fmaxf(fmaf(dn, a[6], bb1.z), 0.f);
    float r7 = fmaxf(fmaf(dn, a[7], bb1.w), 0.f);
    if (BF16OUT) {
        uint4 o;
        o.x = (uint32)f2bf(r0) | ((uint32)f2bf(r1) << 16);
        o.y = (uint32)f2bf(r2) | ((uint32)f2bf(r3) << 16);
        o.z = (uint32)f2bf(r4) | ((uint32)f2bf(r5) << 16);
        o.w = (uint32)f2bf(r6) | ((uint32)f2bf(r7) << 16);
        ((uint4*)Hout)[(size_t)n * 16 + li] = o;
    } else {
        float4* H4 = (float4*)Hout;
        float4 o0; o0.x = r0; o0.y = r1; o0.z = r2; o0.w = r3;
        float4 o1; o1.x = r4; o1.y = r5; o1.z = r6; o1.w = r7;
        H4[(size_t)n * 32 + li * 2]     = o0;
        H4[(size_t)n * 32 + li * 2 + 1] = o1;
    }
}

extern "C" void kernel_launch(void* const* d_in, const int* in_sizes, int n_in,
                              void* d_out, int out_size, void* d_ws, size_t ws_size,
                              hipStream_t stream) {
    const float* x  = (const float*)d_in[0];
    const int*   ei = (const int*)d_in[1];   // int32 per harness contract
    const float* W1 = (const float*)d_in[2];
    const float* b1 = (const float*)d_in[3];
    const float* W2 = (const float*)d_in[4];
    const float* b2 = (const float*)d_in[5];
    float* out = (float*)d_out;

    char* ws = (char*)d_ws;
    size_t off = 0;
    auto alloc = [&](size_t bytes) -> void* {
        void* p = ws + off;
        off += (bytes + 255) & ~(size_t)255;
        return p;
    };
    int*    histM    = (int*)alloc((size_t)LHM * 4);
    int*    base     = (int*)alloc((size_t)LHM * 4);
    int*    bsum     = (int*)alloc((size_t)NSB * 4);
    int*    rowstart = (int*)alloc((size_t)(N_NODES + 1) * 4);
    float*  dis      = (float*)alloc((size_t)N_NODES * 4);
    uint32* edgeTmp  = (uint32*)alloc((size_t)N_EDGES * 4);
    ushort* e16      = (ushort*)alloc((size_t)N_EDGES * 2);
    ushort* Hb       = (ushort*)alloc((size_t)N_NODES * D * 2);
    ushort* HO1      = (ushort*)alloc((size_t)N_NODES * D * 2);   // layer-1 out bf16
    ushort* W1t      = (ushort*)alloc((size_t)D * D * 2);
    ushort* W2t      = (ushort*)alloc((size_t)D * D * 2);
    int*    dhist    = (int*)alloc((size_t)NBIN * BPAD * 4);
    int*    dcur     = (int*)alloc((size_t)NBIN * BPAD * 4);
    int*    perm     = (int*)alloc((size_t)N_NODES * 4);

    const int* src = ei;             // edge_index[0]
    const int* dst = ei + N_EDGES;   // edge_index[1]

    phaseA_kernel<<<NB + 3, 256, 0, stream>>>(dst, histM, W1, W2, W1t, W2t, dhist);
    scan1g<<<NSB, 256, 0, stream>>>(histM, base, bsum);
    scan23g<<<NSB, 256, 0, stream>>>(base, bsum);
    phaseC_kernel<<<NB, 256, 0, stream>>>(src, dst, base, edgeTmp);
    phaseD_kernel<<<NBKT, 256, 0, stream>>>(edgeTmp, base, rowstart, dis, e16, dhist);
    scandeg_kernel<<<1, 128, 0, stream>>>(dhist, dcur);
    permbuild_kernel<<<(N_NODES + 255) / 256, 256, 0, stream>>>(rowstart, dcur, perm);

    gemm_mfma<false><<<GB, 256, 0, stream>>>(x, W1t, dis, Hb);
    aggr_kernel<true><<<PB, 256, 0, stream>>>((const uint4*)Hb, dis, rowstart,
                                              e16, perm, b1, HO1);
    gemm_mfma<true><<<GB, 256, 0, stream>>>(HO1, W2t, dis, Hb);
    aggr_kernel<false><<<PB, 256, 0, stream>>>((const uint4*)Hb, dis, rowstart,
                                               e16, perm, b2, out);
}

// Round 4
// 209.330 us; speedup vs baseline: 1.2189x; 1.0388x over previous
//
#include <hip/hip_runtime.h>

#define N_NODES 50000
#define N_EDGES 800000
#define D 128
#define NB 392            // partition chunk blocks (full CU coverage)
#define CHUNK 2048        // edges per chunk (392*2048 = 802816 >= 800000)
#define NBKT 391          // buckets = dst>>7 (128 nodes each)
#define LHM (NBKT * NB)   // hist matrix length 153272
#define NSB ((LHM + 255) / 256)   // 599
#define PB 3125           // final aggr blocks: 3125*16 = 50000 nodes

typedef unsigned int uint32;
typedef unsigned short ushort;
typedef __attribute__((ext_vector_type(8))) short s8v;   // 8 x bf16 bits
typedef __attribute__((ext_vector_type(4))) float f4v;   // MFMA accumulator

__device__ __forceinline__ ushort f2bf(float f) {   // RNE bf16
    unsigned u = __float_as_uint(f);
    u += 0x7FFFu + ((u >> 16) & 1u);
    return (ushort)(u >> 16);
}
__device__ __forceinline__ float bf_lo(uint32 u) { return __uint_as_float(u << 16); }
__device__ __forceinline__ float bf_hi(uint32 u) { return __uint_as_float(u & 0xFFFF0000u); }

// ---- block-wide inclusive scan helper (256 threads = 4 waves) ----
__device__ __forceinline__ int block_incl_scan(int v, int t) {
    int lane = t & 63, wv = t >> 6;
    int incl = v;
    #pragma unroll
    for (int off = 1; off < 64; off <<= 1) {
        int u = __shfl_up(incl, off, 64);
        if (lane >= off) incl += u;
    }
    __shared__ int wsums[4];
    if (lane == 63) wsums[wv] = incl;
    __syncthreads();
    int add = 0;
    if (wv > 0) add += wsums[0];
    if (wv > 1) add += wsums[1];
    if (wv > 2) add += wsums[2];
    return incl + add;
}

// ---- K1: per-chunk bucket histogram (private slots, NO global atomics) + wprep ----
__global__ __launch_bounds__(256) void phaseA_kernel(const int* __restrict__ dst,
                                                     int* __restrict__ histM,
                                                     const float* __restrict__ W1,
                                                     const float* __restrict__ W2,
                                                     ushort* __restrict__ W1t,
                                                     ushort* __restrict__ W2t) {
    int t = threadIdx.x, blk = blockIdx.x;
    if (blk >= NB) {                      // 2 tail blocks: weight transpose+cvt
        const float* W = (blk - NB) ? W2 : W1;
        ushort* Wt = (blk - NB) ? W2t : W1t;
        #pragma unroll
        for (int it = 0; it < 16; it++) {
            int fid = t + it * 256;       // float4 id 0..4095
            int k = fid >> 5;
            int n0 = (fid & 31) * 4;
            float4 w = ((const float4*)W)[fid];
            Wt[(n0 + 0) * D + k] = f2bf(w.x);
            Wt[(n0 + 1) * D + k] = f2bf(w.y);
            Wt[(n0 + 2) * D + k] = f2bf(w.z);
            Wt[(n0 + 3) * D + k] = f2bf(w.w);
        }
        return;
    }
    __shared__ int lc[NBKT];
    for (int i = t; i < NBKT; i += 256) lc[i] = 0;
    __syncthreads();
    int e0 = blk * CHUNK;
    #pragma unroll
    for (int j = 0; j < 8; j++) {
        int e = e0 + t + j * 256;
        if (e < N_EDGES) atomicAdd(&lc[dst[e] >> 7], 1);
    }
    __syncthreads();
    for (int i = t; i < NBKT; i += 256)
        histM[i * NB + blk] = lc[i];      // bucket-major, block-minor (private slot)
}

// ---- scan pass 1: block-local exclusive + block sums ----
__global__ __launch_bounds__(256) void scan1g(const int* __restrict__ in,
                                              int* __restrict__ out,
                                              int* __restrict__ bsum) {
    int t = threadIdx.x, blk = blockIdx.x;
    int i = blk * 256 + t;
    int v = (i < LHM) ? in[i] : 0;
    int incl = block_incl_scan(v, t);
    if (i < LHM) out[i] = incl - v;
    if (t == 255) bsum[blk] = incl;
}

// ---- scan pass 2 (merged): each block reduces its bsum-prefix, adds to its tile ----
__global__ __launch_bounds__(256) void scan23g(int* __restrict__ out,
                                               const int* __restrict__ bsum) {
    int t = threadIdx.x, blk = blockIdx.x;
    int local = 0;
    for (int i = t; i < blk; i += 256) local += bsum[i];
    int lane = t & 63, wv = t >> 6;
    #pragma unroll
    for (int off = 32; off > 0; off >>= 1) local += __shfl_down(local, off, 64);
    __shared__ int ws[4];
    if (lane == 0) ws[wv] = local;
    __syncthreads();
    int boff = ws[0] + ws[1] + ws[2] + ws[3];
    int i = blk * 256 + t;
    if (i < LHM) out[i] += boff;
}

// ---- K3: phaseC — partition edges into bucket-major order (no global atomics) ----
__global__ __launch_bounds__(256) void phaseC_kernel(const int* __restrict__ src,
                                                     const int* __restrict__ dst,
                                                     const int* __restrict__ base,
                                                     uint32* __restrict__ edgeTmp) {
    __shared__ int cur[NBKT];
    int t = threadIdx.x, blk = blockIdx.x;
    for (int i = t; i < NBKT; i += 256) cur[i] = base[i * NB + blk];
    __syncthreads();
    int e0 = blk * CHUNK;
    #pragma unroll
    for (int j = 0; j < 8; j++) {
        int e = e0 + t + j * 256;
        if (e < N_EDGES) {
            uint32 s = (uint32)src[e], d = (uint32)dst[e];
            int p = atomicAdd(&cur[d >> 7], 1);      // LDS atomic
            edgeTmp[p] = (s << 16) | d;              // both < 65536
        }
    }
}

// ---- K4 FUSED: per-bucket counting sort + rowstart + dis + e16, THEN gemm1 on the
// same 128 rows (bucket b == gemm tile b; dis consumed from LDS, never re-read) ----
__global__ __launch_bounds__(256) void phaseDG_kernel(const uint32* __restrict__ edgeTmp,
                                                      const int* __restrict__ base,
                                                      int* __restrict__ rowstart,
                                                      float* __restrict__ dis,
                                                      ushort* __restrict__ e16,
                                                      const float* __restrict__ X,
                                                      const ushort* __restrict__ Wt,
                                                      ushort* __restrict__ Hb) {
    __shared__ int cnt[128];
    __shared__ int cur[128];
    __shared__ float disS[128];
    __shared__ ushort Cs[128 * 136];
    int t = threadIdx.x, b = blockIdx.x;
    int beg = base[b * NB];
    int end = (b == NBKT - 1) ? N_EDGES : base[(b + 1) * NB];
    if (t < 128) cnt[t] = 0;
    __syncthreads();
    for (int p = beg + t; p < end; p += 256)
        atomicAdd(&cnt[edgeTmp[p] & 127], 1);
    __syncthreads();
    int c = (t < 128) ? cnt[t] : 0;
    int incl = block_incl_scan(c, t);
    int excl = incl - c;
    int node = b * 128 + t;
    if (t < 128) {
        if (node <= N_NODES) rowstart[node] = beg + excl;
        float dv = rsqrtf((float)(c + 1));
        if (node < N_NODES) dis[node] = dv;
        disS[t] = dv;
        cur[t] = excl;
    }
    __syncthreads();
    for (int p = beg + t; p < end; p += 256) {
        uint32 u = edgeTmp[p];
        int r = atomicAdd(&cur[u & 127], 1);            // LDS atomic
        e16[beg + r] = (ushort)(u >> 16);
    }
    // ---- gemm1: Hb[rows of bucket b] = bf16(disS * (X @ W1)) ----
    int wv = t >> 6, lane = t & 63;
    int q = lane >> 4, m = lane & 15;
    int rbase = b * 128 + wv * 32;
    f4v zero = {0.f, 0.f, 0.f, 0.f};
    f4v acc[2][8];
    #pragma unroll
    for (int mt = 0; mt < 2; mt++)
        #pragma unroll
        for (int n = 0; n < 8; n++) acc[mt][n] = zero;
    #pragma unroll
    for (int kt = 0; kt < 4; kt++) {
        int k0 = kt * 32 + q * 8;
        s8v a[2];
        #pragma unroll
        for (int mt = 0; mt < 2; mt++) {
            int row = rbase + mt * 16 + m;
            if (row >= N_NODES) row = N_NODES - 1;
            const float* xp = X + (size_t)row * D + k0;
            float4 u0 = *(const float4*)xp;
            float4 u1 = *(const float4*)(xp + 4);
            s8v av;
            av[0] = (short)f2bf(u0.x); av[1] = (short)f2bf(u0.y);
            av[2] = (short)f2bf(u0.z); av[3] = (short)f2bf(u0.w);
            av[4] = (short)f2bf(u1.x); av[5] = (short)f2bf(u1.y);
            av[6] = (short)f2bf(u1.z); av[7] = (short)f2bf(u1.w);
            a[mt] = av;
        }
        #pragma unroll
        for (int n = 0; n < 8; n++) {
            s8v bb = *(const s8v*)(Wt + (size_t)(n * 16 + m) * D + k0);
            acc[0][n] = __builtin_amdgcn_mfma_f32_16x16x32_bf16(a[0], bb, acc[0][n], 0, 0, 0);
            acc[1][n] = __builtin_amdgcn_mfma_f32_16x16x32_bf16(a[1], bb, acc[1][n], 0, 0, 0);
        }
    }
    __syncthreads();   // e16 loop done; Cs free to use
    #pragma unroll
    for (int mt = 0; mt < 2; mt++)
        #pragma unroll
        for (int n = 0; n < 8; n++)
            #pragma unroll
            for (int r = 0; r < 4; r++) {
                int lr = wv * 32 + mt * 16 + q * 4 + r;
                Cs[lr * 136 + n * 16 + m] = f2bf(acc[mt][n][r] * disS[lr]);
            }
    __syncthreads();
    int gbase = b * 128;
    #pragma unroll
    for (int it = 0; it < 8; it++) {
        int cid = t + it * 256;
        int row = cid >> 4, off = (cid & 15) * 8;
        int grow = gbase + row;
        if (grow < N_NODES) {
            s8v v = *(const s8v*)(Cs + row * 136 + off);
            *(s8v*)(Hb + (size_t)grow * D + off) = v;
        }
    }
}

// ---- helpers for aggregation ----
__device__ __forceinline__ void acc8(float* a, uint4 v) {
    a[0] += bf_lo(v.x); a[1] += bf_hi(v.x);
    a[2] += bf_lo(v.y); a[3] += bf_hi(v.y);
    a[4] += bf_lo(v.z); a[5] += bf_hi(v.z);
    a[6] += bf_lo(v.w); a[7] += bf_hi(v.w);
}

// ---- K5 FUSED: aggr layer-1 (128 nodes -> relu'd HO1 rows in LDS) + gemm2 ----
// HO1 never touches global memory (saves 25.6 MB round-trip). Per-block gather work
// = sum of 128 node degrees ~= 2048 +/- 2% -> naturally load-balanced.
__global__ __launch_bounds__(256) void aggrG_kernel(const uint4* __restrict__ Hb4,
                                                    const float* __restrict__ dis,
                                                    const int* __restrict__ rowstart,
                                                    const ushort* __restrict__ e16,
                                                    const float* __restrict__ bias,
                                                    const ushort* __restrict__ Wt,
                                                    ushort* __restrict__ Hb2) {
    __shared__ ushort Cs[128 * 136];
    __shared__ float disS[128];
    int t = threadIdx.x, blk = blockIdx.x;
    int li = t & 15, g = t >> 4;           // 16 groups of 16 lanes
    const float4* b4 = (const float4*)bias;
    float4 bb0 = b4[li * 2], bb1 = b4[li * 2 + 1];
    #pragma unroll 1
    for (int pass = 0; pass < 8; pass++) {
        int local = pass * 16 + g;
        int n = blk * 128 + local;
        if (n < N_NODES) {
            float dn = dis[n];
            if (li == 0) disS[local] = dn;
            float a[8];
            {
                uint4 sv = Hb4[(size_t)n * 16 + li];   // self term (dis folded)
                a[0] = bf_lo(sv.x); a[1] = bf_hi(sv.x);
                a[2] = bf_lo(sv.y); a[3] = bf_hi(sv.y);
                a[4] = bf_lo(sv.z); a[5] = bf_hi(sv.z);
                a[6] = bf_lo(sv.w); a[7] = bf_hi(sv.w);
            }
            int beg = rowstart[n], end = rowstart[n + 1];
            int p = beg;
            for (; p + 7 < end; p += 8) {  // 8 outstanding 16B gathers per lane
                int s[8];
                #pragma unroll
                for (int j = 0; j < 8; j++) s[j] = e16[p + j];
                uint4 v[8];
                #pragma unroll
                for (int j = 0; j < 8; j++) v[j] = Hb4[(size_t)s[j] * 16 + li];
                #pragma unroll
                for (int j = 0; j < 8; j++) acc8(a, v[j]);
            }
            for (; p + 3 < end; p += 4) {
                int s0 = e16[p + 0], s1 = e16[p + 1], s2 = e16[p + 2], s3 = e16[p + 3];
                uint4 v0 = Hb4[(size_t)s0 * 16 + li];
                uint4 v1 = Hb4[(size_t)s1 * 16 + li];
                uint4 v2 = Hb4[(size_t)s2 * 16 + li];
                uint4 v3 = Hb4[(size_t)s3 * 16 + li];
                acc8(a, v0); acc8(a, v1); acc8(a, v2); acc8(a, v3);
            }
            for (; p < end; p++) {
                uint4 v0 = Hb4[(size_t)e16[p] * 16 + li];
                acc8(a, v0);
            }
            s8v o;
            o[0] = (short)f2bf(fmaxf(fmaf(dn, a[0], bb0.x), 0.f));
            o[1] = (short)f2bf(fmaxf(fmaf(dn, a[1], bb0.y), 0.f));
            o[2] = (short)f2bf(fmaxf(fmaf(dn, a[2], bb0.z), 0.f));
            o[3] = (short)f2bf(fmaxf(fmaf(dn, a[3], bb0.w), 0.f));
            o[4] = (short)f2bf(fmaxf(fmaf(dn, a[4], bb1.x), 0.f));
            o[5] = (short)f2bf(fmaxf(fmaf(dn, a[5], bb1.y), 0.f));
            o[6] = (short)f2bf(fmaxf(fmaf(dn, a[6], bb1.z), 0.f));
            o[7] = (short)f2bf(fmaxf(fmaf(dn, a[7], bb1.w), 0.f));
            *(s8v*)(Cs + local * 136 + li * 8) = o;    // HO1 row -> LDS only
        } else {
            s8v z = {0, 0, 0, 0, 0, 0, 0, 0};
            if (li == 0) disS[local] = 0.f;
            *(s8v*)(Cs + local * 136 + li * 8) = z;
        }
    }
    __syncthreads();
    // ---- gemm2: Hb2[rows] = bf16(disS * (HO1 @ W2)), A-fragments from LDS ----
    int wv = t >> 6, lane = t & 63;
    int q = lane >> 4, m = lane & 15;
    int rloc = wv * 32;
    f4v zero = {0.f, 0.f, 0.f, 0.f};
    f4v acc[2][8];
    #pragma unroll
    for (int mt = 0; mt < 2; mt++)
        #pragma unroll
        for (int n = 0; n < 8; n++) acc[mt][n] = zero;
    #pragma unroll
    for (int kt = 0; kt < 4; kt++) {
        int k0 = kt * 32 + q * 8;
        s8v a[2];
        #pragma unroll
        for (int mt = 0; mt < 2; mt++)
            a[mt] = *(const s8v*)(Cs + (rloc + mt * 16 + m) * 136 + k0);
        #pragma unroll
        for (int n = 0; n < 8; n++) {
            s8v bb = *(const s8v*)(Wt + (size_t)(n * 16 + m) * D + k0);
            acc[0][n] = __builtin_amdgcn_mfma_f32_16x16x32_bf16(a[0], bb, acc[0][n], 0, 0, 0);
            acc[1][n] = __builtin_amdgcn_mfma_f32_16x16x32_bf16(a[1], bb, acc[1][n], 0, 0, 0);
        }
    }
    __syncthreads();   // all A-reads done; Cs reusable for C staging
    #pragma unroll
    for (int mt = 0; mt < 2; mt++)
        #pragma unroll
        for (int n = 0; n < 8; n++)
            #pragma unroll
            for (int r = 0; r < 4; r++) {
                int lr = wv * 32 + mt * 16 + q * 4 + r;
                Cs[lr * 136 + n * 16 + m] = f2bf(acc[mt][n][r] * disS[lr]);
            }
    __syncthreads();
    int gbase = blk * 128;
    #pragma unroll
    for (int it = 0; it < 8; it++) {
        int cid = t + it * 256;
        int row = cid >> 4, off = (cid & 15) * 8;
        int grow = gbase + row;
        if (grow < N_NODES) {
            s8v v = *(const s8v*)(Cs + row * 136 + off);
            *(s8v*)(Hb2 + (size_t)grow * D + off) = v;
        }
    }
}

// ---- K6: final aggregate: out = relu(dis[n]*(Hb2[n]+sum Hb2[src])+b2), f32 out ----
__global__ __launch_bounds__(256) void aggr_kernel(const uint4* __restrict__ Hb4,
                                                   const float* __restrict__ dis,
                                                   const int* __restrict__ rowstart,
                                                   const ushort* __restrict__ e16,
                                                   const float* __restrict__ bias,
                                                   float* __restrict__ Hout) {
    int t = threadIdx.x;
    int li = t & 15;                       // lane in group: channels li*8..li*8+7
    int n = blockIdx.x * 16 + (t >> 4);    // 50000 = 3125*16
    float dn = dis[n];
    float a[8];
    {
        uint4 sv = Hb4[(size_t)n * 16 + li];   // self term (dis folded)
        a[0] = bf_lo(sv.x); a[1] = bf_hi(sv.x);
        a[2] = bf_lo(sv.y); a[3] = bf_hi(sv.y);
        a[4] = bf_lo(sv.z); a[5] = bf_hi(sv.z);
        a[6] = bf_lo(sv.w); a[7] = bf_hi(sv.w);
    }
    int beg = rowstart[n], end = rowstart[n + 1];
    int p = beg;
    for (; p + 7 < end; p += 8) {
        int s[8];
        #pragma unroll
        for (int j = 0; j < 8; j++) s[j] = e16[p + j];
        uint4 v[8];
        #pragma unroll
        for (int j = 0; j < 8; j++) v[j] = Hb4[(size_t)s[j] * 16 + li];
        #pragma unroll
        for (int j = 0; j < 8; j++) acc8(a, v[j]);
    }
    for (; p + 3 < end; p += 4) {
        int s0 = e16[p + 0], s1 = e16[p + 1], s2 = e16[p + 2], s3 = e16[p + 3];
        uint4 v0 = Hb4[(size_t)s0 * 16 + li];
        uint4 v1 = Hb4[(size_t)s1 * 16 + li];
        uint4 v2 = Hb4[(size_t)s2 * 16 + li];
        uint4 v3 = Hb4[(size_t)s3 * 16 + li];
        acc8(a, v0); acc8(a, v1); acc8(a, v2); acc8(a, v3);
    }
    for (; p < end; p++) {
        uint4 v0 = Hb4[(size_t)e16[p] * 16 + li];
        acc8(a, v0);
    }
    const float4* b4 = (const float4*)bias;
    float4 bb0 = b4[li * 2], bb1 = b4[li * 2 + 1];
    float4 o0, o1;
    o0.x = fmaxf(fmaf(dn, a[0], bb0.x), 0.f);
    o0.y = fmaxf(fmaf(dn, a[1], bb0.y), 0.f);
    o0.z = fmaxf(fmaf(dn, a[2], bb0.z), 0.f);
    o0.w = fmaxf(fmaf(dn, a[3], bb0.w), 0.f);
    o1.x = fmaxf(fmaf(dn, a[4], bb1.x), 0.f);
    o1.y = fmaxf(fmaf(dn, a[5], bb1.y), 0.f);
    o1.z = fmaxf(fmaf(dn, a[6], bb1.z), 0.f);
    o1.w = fmaxf(fmaf(dn, a[7], bb1.w), 0.f);
    float4* H4 = (float4*)Hout;
    H4[(size_t)n * 32 + li * 2]     = o0;
    H4[(size_t)n * 32 + li * 2 + 1] = o1;
}

extern "C" void kernel_launch(void* const* d_in, const int* in_sizes, int n_in,
                              void* d_out, int out_size, void* d_ws, size_t ws_size,
                              hipStream_t stream) {
    const float* x  = (const float*)d_in[0];
    const int*   ei = (const int*)d_in[1];   // int32 per harness contract
    const float* W1 = (const float*)d_in[2];
    const float* b1 = (const float*)d_in[3];
    const float* W2 = (const float*)d_in[4];
    const float* b2 = (const float*)d_in[5];
    float* out = (float*)d_out;

    char* ws = (char*)d_ws;
    size_t off = 0;
    auto alloc = [&](size_t bytes) -> void* {
        void* p = ws + off;
        off += (bytes + 255) & ~(size_t)255;
        return p;
    };
    int*    histM    = (int*)alloc((size_t)LHM * 4);
    int*    base     = (int*)alloc((size_t)LHM * 4);
    int*    bsum     = (int*)alloc((size_t)NSB * 4);
    int*    rowstart = (int*)alloc((size_t)(N_NODES + 1) * 4);
    float*  dis      = (float*)alloc((size_t)N_NODES * 4);
    uint32* edgeTmp  = (uint32*)alloc((size_t)N_EDGES * 4);
    ushort* e16      = (ushort*)alloc((size_t)N_EDGES * 2);
    ushort* Hb       = (ushort*)alloc((size_t)N_NODES * D * 2);
    ushort* Hb2      = (ushort*)alloc((size_t)N_NODES * D * 2);
    ushort* W1t      = (ushort*)alloc((size_t)D * D * 2);
    ushort* W2t      = (ushort*)alloc((size_t)D * D * 2);

    const int* src = ei;             // edge_index[0]
    const int* dst = ei + N_EDGES;   // edge_index[1]

    phaseA_kernel<<<NB + 2, 256, 0, stream>>>(dst, histM, W1, W2, W1t, W2t);
    scan1g<<<NSB, 256, 0, stream>>>(histM, base, bsum);
    scan23g<<<NSB, 256, 0, stream>>>(base, bsum);
    phaseC_kernel<<<NB, 256, 0, stream>>>(src, dst, base, edgeTmp);
    phaseDG_kernel<<<NBKT, 256, 0, stream>>>(edgeTmp, base, rowstart, dis, e16,
                                             x, W1t, Hb);
    aggrG_kernel<<<NBKT, 256, 0, stream>>>((const uint4*)Hb, dis, rowstart, e16,
                                           b1, W2t, Hb2);
    aggr_kernel<<<PB, 256, 0, stream>>>((const uint4*)Hb2, dis, rowstart, e16,
                                        b2, out);
}

// Round 5
// 202.320 us; speedup vs baseline: 1.2612x; 1.0346x over previous
//
#include <hip/hip_runtime.h>

#define N_NODES 50000
#define N_EDGES 800000
#define D 128
#define NB 392            // partition chunk blocks (full CU coverage)
#define CHUNK 2048        // edges per chunk (392*2048 = 802816 >= 800000)
#define NBKT 391          // buckets = dst>>7 (128 nodes each)
#define LHM (NBKT * NB)   // hist matrix length 153272
#define NSB ((LHM + 255) / 256)   // 599
#define GB ((N_NODES + 127) / 128)   // 391 gemm tiles
#define PB 3125           // aggr blocks: 3125*16 = 50000 nodes (gather NEEDS >=3000
                          // blocks: fusing it into 391-block tiles measured 55 vs 38us)

typedef unsigned int uint32;
typedef unsigned short ushort;
typedef __attribute__((ext_vector_type(8))) short s8v;   // 8 x bf16 bits
typedef __attribute__((ext_vector_type(4))) float f4v;   // MFMA accumulator

__device__ __forceinline__ ushort f2bf(float f) {   // RNE bf16
    unsigned u = __float_as_uint(f);
    u += 0x7FFFu + ((u >> 16) & 1u);
    return (ushort)(u >> 16);
}
__device__ __forceinline__ float bf_lo(uint32 u) { return __uint_as_float(u << 16); }
__device__ __forceinline__ float bf_hi(uint32 u) { return __uint_as_float(u & 0xFFFF0000u); }

// ---- block-wide inclusive scan helper (256 threads = 4 waves) ----
__device__ __forceinline__ int block_incl_scan(int v, int t) {
    int lane = t & 63, wv = t >> 6;
    int incl = v;
    #pragma unroll
    for (int off = 1; off < 64; off <<= 1) {
        int u = __shfl_up(incl, off, 64);
        if (lane >= off) incl += u;
    }
    __shared__ int wsums[4];
    if (lane == 63) wsums[wv] = incl;
    __syncthreads();
    int add = 0;
    if (wv > 0) add += wsums[0];
    if (wv > 1) add += wsums[1];
    if (wv > 2) add += wsums[2];
    return incl + add;
}

// ---- K1: per-chunk bucket histogram (private slots, NO global atomics) + wprep ----
__global__ __launch_bounds__(256) void phaseA_kernel(const int* __restrict__ dst,
                                                     int* __restrict__ histM,
                                                     const float* __restrict__ W1,
                                                     const float* __restrict__ W2,
                                                     ushort* __restrict__ W1t,
                                                     ushort* __restrict__ W2t) {
    int t = threadIdx.x, blk = blockIdx.x;
    if (blk >= NB) {                      // 2 tail blocks: weight transpose+cvt
        const float* W = (blk - NB) ? W2 : W1;
        ushort* Wt = (blk - NB) ? W2t : W1t;
        #pragma unroll
        for (int it = 0; it < 16; it++) {
            int fid = t + it * 256;       // float4 id 0..4095
            int k = fid >> 5;
            int n0 = (fid & 31) * 4;
            float4 w = ((const float4*)W)[fid];
            Wt[(n0 + 0) * D + k] = f2bf(w.x);
            Wt[(n0 + 1) * D + k] = f2bf(w.y);
            Wt[(n0 + 2) * D + k] = f2bf(w.z);
            Wt[(n0 + 3) * D + k] = f2bf(w.w);
        }
        return;
    }
    __shared__ int lc[NBKT];
    for (int i = t; i < NBKT; i += 256) lc[i] = 0;
    __syncthreads();
    int e0 = blk * CHUNK;
    #pragma unroll
    for (int j = 0; j < 8; j++) {
        int e = e0 + t + j * 256;
        if (e < N_EDGES) atomicAdd(&lc[dst[e] >> 7], 1);
    }
    __syncthreads();
    for (int i = t; i < NBKT; i += 256)
        histM[i * NB + blk] = lc[i];      // bucket-major, block-minor (private slot)
}

// ---- scan pass 1: block-local exclusive + block sums ----
__global__ __launch_bounds__(256) void scan1g(const int* __restrict__ in,
                                              int* __restrict__ out,
                                              int* __restrict__ bsum) {
    int t = threadIdx.x, blk = blockIdx.x;
    int i = blk * 256 + t;
    int v = (i < LHM) ? in[i] : 0;
    int incl = block_incl_scan(v, t);
    if (i < LHM) out[i] = incl - v;
    if (t == 255) bsum[blk] = incl;
}

// ---- scan pass 2 (merged): each block reduces its bsum-prefix, adds to its tile ----
__global__ __launch_bounds__(256) void scan23g(int* __restrict__ out,
                                               const int* __restrict__ bsum) {
    int t = threadIdx.x, blk = blockIdx.x;
    int local = 0;
    for (int i = t; i < blk; i += 256) local += bsum[i];
    int lane = t & 63, wv = t >> 6;
    #pragma unroll
    for (int off = 32; off > 0; off >>= 1) local += __shfl_down(local, off, 64);
    __shared__ int ws[4];
    if (lane == 0) ws[wv] = local;
    __syncthreads();
    int boff = ws[0] + ws[1] + ws[2] + ws[3];
    int i = blk * 256 + t;
    if (i < LHM) out[i] += boff;
}

// ---- K3: phaseC — partition edges into bucket-major order (no global atomics) ----
__global__ __launch_bounds__(256) void phaseC_kernel(const int* __restrict__ src,
                                                     const int* __restrict__ dst,
                                                     const int* __restrict__ base,
                                                     uint32* __restrict__ edgeTmp) {
    __shared__ int cur[NBKT];
    int t = threadIdx.x, blk = blockIdx.x;
    for (int i = t; i < NBKT; i += 256) cur[i] = base[i * NB + blk];
    __syncthreads();
    int e0 = blk * CHUNK;
    #pragma unroll
    for (int j = 0; j < 8; j++) {
        int e = e0 + t + j * 256;
        if (e < N_EDGES) {
            uint32 s = (uint32)src[e], d = (uint32)dst[e];
            int p = atomicAdd(&cur[d >> 7], 1);      // LDS atomic
            edgeTmp[p] = (s << 16) | d;              // both < 65536
        }
    }
}

// ---- K4 FUSED: per-bucket counting sort + rowstart + dis + e16, THEN gemm1 on the
// same 128 rows (bucket b == gemm tile b; dis consumed from LDS, never re-read) ----
__global__ __launch_bounds__(256) void phaseDG_kernel(const uint32* __restrict__ edgeTmp,
                                                      const int* __restrict__ base,
                                                      int* __restrict__ rowstart,
                                                      float* __restrict__ dis,
                                                      ushort* __restrict__ e16,
                                                      const float* __restrict__ X,
                                                      const ushort* __restrict__ Wt,
                                                      ushort* __restrict__ Hb) {
    __shared__ int cnt[128];
    __shared__ int cur[128];
    __shared__ float disS[128];
    __shared__ ushort Cs[128 * 136];
    int t = threadIdx.x, b = blockIdx.x;
    int beg = base[b * NB];
    int end = (b == NBKT - 1) ? N_EDGES : base[(b + 1) * NB];
    if (t < 128) cnt[t] = 0;
    __syncthreads();
    for (int p = beg + t; p < end; p += 256)
        atomicAdd(&cnt[edgeTmp[p] & 127], 1);
    __syncthreads();
    int c = (t < 128) ? cnt[t] : 0;
    int incl = block_incl_scan(c, t);
    int excl = incl - c;
    int node = b * 128 + t;
    if (t < 128) {
        if (node <= N_NODES) rowstart[node] = beg + excl;
        float dv = rsqrtf((float)(c + 1));
        if (node < N_NODES) dis[node] = dv;
        disS[t] = dv;
        cur[t] = excl;
    }
    __syncthreads();
    for (int p = beg + t; p < end; p += 256) {
        uint32 u = edgeTmp[p];
        int r = atomicAdd(&cur[u & 127], 1);            // LDS atomic
        e16[beg + r] = (ushort)(u >> 16);
    }
    // ---- gemm1: Hb[rows of bucket b] = bf16(disS * (X @ W1)) ----
    int wv = t >> 6, lane = t & 63;
    int q = lane >> 4, m = lane & 15;
    int rbase = b * 128 + wv * 32;
    f4v zero = {0.f, 0.f, 0.f, 0.f};
    f4v acc[2][8];
    #pragma unroll
    for (int mt = 0; mt < 2; mt++)
        #pragma unroll
        for (int n = 0; n < 8; n++) acc[mt][n] = zero;
    #pragma unroll
    for (int kt = 0; kt < 4; kt++) {
        int k0 = kt * 32 + q * 8;
        s8v a[2];
        #pragma unroll
        for (int mt = 0; mt < 2; mt++) {
            int row = rbase + mt * 16 + m;
            if (row >= N_NODES) row = N_NODES - 1;
            const float* xp = X + (size_t)row * D + k0;
            float4 u0 = *(const float4*)xp;
            float4 u1 = *(const float4*)(xp + 4);
            s8v av;
            av[0] = (short)f2bf(u0.x); av[1] = (short)f2bf(u0.y);
            av[2] = (short)f2bf(u0.z); av[3] = (short)f2bf(u0.w);
            av[4] = (short)f2bf(u1.x); av[5] = (short)f2bf(u1.y);
            av[6] = (short)f2bf(u1.z); av[7] = (short)f2bf(u1.w);
            a[mt] = av;
        }
        #pragma unroll
        for (int n = 0; n < 8; n++) {
            s8v bb = *(const s8v*)(Wt + (size_t)(n * 16 + m) * D + k0);
            acc[0][n] = __builtin_amdgcn_mfma_f32_16x16x32_bf16(a[0], bb, acc[0][n], 0, 0, 0);
            acc[1][n] = __builtin_amdgcn_mfma_f32_16x16x32_bf16(a[1], bb, acc[1][n], 0, 0, 0);
        }
    }
    __syncthreads();   // e16 loop done; Cs free to use
    #pragma unroll
    for (int mt = 0; mt < 2; mt++)
        #pragma unroll
        for (int n = 0; n < 8; n++)
            #pragma unroll
            for (int r = 0; r < 4; r++) {
                int lr = wv * 32 + mt * 16 + q * 4 + r;
                Cs[lr * 136 + n * 16 + m] = f2bf(acc[mt][n][r] * disS[lr]);
            }
    __syncthreads();
    int gbase = b * 128;
    #pragma unroll
    for (int it = 0; it < 8; it++) {
        int cid = t + it * 256;
        int row = cid >> 4, off = (cid & 15) * 8;
        int grow = gbase + row;
        if (grow < N_NODES) {
            s8v v = *(const s8v*)(Cs + row * 136 + off);
            *(s8v*)(Hb + (size_t)grow * D + off) = v;
        }
    }
}

// ---- standalone gemm2: Hb2 = bf16(dis * (HO1 @ W2)), bf16 input ----
__global__ __launch_bounds__(256) void gemm_mfma(const ushort* __restrict__ Xb,
                                                 const ushort* __restrict__ Wt,
                                                 const float* __restrict__ dis,
                                                 ushort* __restrict__ Hb) {
    __shared__ ushort Cs[128 * 136];
    int t = threadIdx.x;
    int wv = t >> 6, lane = t & 63;
    int q = lane >> 4, m = lane & 15;
    int rbase = blockIdx.x * 128 + wv * 32;
    f4v zero = {0.f, 0.f, 0.f, 0.f};
    f4v acc[2][8];
    #pragma unroll
    for (int mt = 0; mt < 2; mt++)
        #pragma unroll
        for (int n = 0; n < 8; n++) acc[mt][n] = zero;

    #pragma unroll
    for (int kt = 0; kt < 4; kt++) {
        int k0 = kt * 32 + q * 8;
        s8v a[2];
        #pragma unroll
        for (int mt = 0; mt < 2; mt++) {
            int row = rbase + mt * 16 + m;
            if (row >= N_NODES) row = N_NODES - 1;
            a[mt] = *(const s8v*)(Xb + (size_t)row * D + k0);   // 16B load
        }
        #pragma unroll
        for (int n = 0; n < 8; n++) {
            s8v b = *(const s8v*)(Wt + (size_t)(n * 16 + m) * D + k0);
            acc[0][n] = __builtin_amdgcn_mfma_f32_16x16x32_bf16(a[0], b, acc[0][n], 0, 0, 0);
            acc[1][n] = __builtin_amdgcn_mfma_f32_16x16x32_bf16(a[1], b, acc[1][n], 0, 0, 0);
        }
    }
    float disv[2][4];
    #pragma unroll
    for (int mt = 0; mt < 2; mt++)
        #pragma unroll
        for (int r = 0; r < 4; r++) {
            int row = rbase + mt * 16 + q * 4 + r;
            if (row >= N_NODES) row = N_NODES - 1;
            disv[mt][r] = dis[row];
        }
    #pragma unroll
    for (int mt = 0; mt < 2; mt++)
        #pragma unroll
        for (int n = 0; n < 8; n++)
            #pragma unroll
            for (int r = 0; r < 4; r++) {
                int row = wv * 32 + mt * 16 + q * 4 + r;
                Cs[row * 136 + n * 16 + m] = f2bf(acc[mt][n][r] * disv[mt][r]);
            }
    __syncthreads();
    int gbase = blockIdx.x * 128;
    #pragma unroll
    for (int it = 0; it < 8; it++) {
        int cid = t + it * 256;
        int row = cid >> 4, off = (cid & 15) * 8;
        int grow = gbase + row;
        if (grow < N_NODES) {
            s8v v = *(const s8v*)(Cs + row * 136 + off);
            *(s8v*)(Hb + (size_t)grow * D + off) = v;
        }
    }
}

// ---- aggregate: out = relu(dis[n]*(Hb[n]+sum Hb[src])+b), 16 lanes/node ----
// PB=3125 blocks (~8 blocks/CU): the gather is latency-bound and needs this grid
// depth (391-block fused variant measured 55us vs 26us). Full 256B-row gathers.
__device__ __forceinline__ void acc8(float* a, uint4 v) {
    a[0] += bf_lo(v.x); a[1] += bf_hi(v.x);
    a[2] += bf_lo(v.y); a[3] += bf_hi(v.y);
    a[4] += bf_lo(v.z); a[5] += bf_hi(v.z);
    a[6] += bf_lo(v.w); a[7] += bf_hi(v.w);
}

template<bool BF16OUT>
__global__ __launch_bounds__(256) void aggr_kernel(const uint4* __restrict__ Hb4,
                                                   const float* __restrict__ dis,
                                                   const int* __restrict__ rowstart,
                                                   const ushort* __restrict__ e16,
                                                   const float* __restrict__ bias,
                                                   void* __restrict__ Hout) {
    int t = threadIdx.x;
    int li = t & 15;                       // lane in group: channels li*8..li*8+7
    int n = blockIdx.x * 16 + (t >> 4);    // 50000 = 3125*16
    float dn = dis[n];
    float a[8];
    {
        uint4 sv = Hb4[(size_t)n * 16 + li];   // self term (dis[n] folded into Hb)
        a[0] = bf_lo(sv.x); a[1] = bf_hi(sv.x);
        a[2] = bf_lo(sv.y); a[3] = bf_hi(sv.y);
        a[4] = bf_lo(sv.z); a[5] = bf_hi(sv.z);
        a[6] = bf_lo(sv.w); a[7] = bf_hi(sv.w);
    }
    int beg = rowstart[n], end = rowstart[n + 1];
    int p = beg;
    for (; p + 7 < end; p += 8) {          // 8 outstanding 16B gathers per lane
        int s[8];
        #pragma unroll
        for (int j = 0; j < 8; j++) s[j] = e16[p + j];
        uint4 v[8];
        #pragma unroll
        for (int j = 0; j < 8; j++) v[j] = Hb4[(size_t)s[j] * 16 + li];
        #pragma unroll
        for (int j = 0; j < 8; j++) acc8(a, v[j]);
    }
    for (; p + 3 < end; p += 4) {
        int s0 = e16[p + 0], s1 = e16[p + 1], s2 = e16[p + 2], s3 = e16[p + 3];
        uint4 v0 = Hb4[(size_t)s0 * 16 + li];
        uint4 v1 = Hb4[(size_t)s1 * 16 + li];
        uint4 v2 = Hb4[(size_t)s2 * 16 + li];
        uint4 v3 = Hb4[(size_t)s3 * 16 + li];
        acc8(a, v0); acc8(a, v1); acc8(a, v2); acc8(a, v3);
    }
    for (; p < end; p++) {
        uint4 v0 = Hb4[(size_t)e16[p] * 16 + li];
        acc8(a, v0);
    }
    const float4* b4 = (const float4*)bias;
    float4 bb0 = b4[li * 2], bb1 = b4[li * 2 + 1];
    float r0 = fmaxf(fmaf(dn, a[0], bb0.x), 0.f);
    float r1 = fmaxf(fmaf(dn, a[1], bb0.y), 0.f);
    float r2 = fmaxf(fmaf(dn, a[2], bb0.z), 0.f);
    float r3 = fmaxf(fmaf(dn, a[3], bb0.w), 0.f);
    float r4 = fmaxf(fmaf(dn, a[4], bb1.x), 0.f);
    float r5 = fmaxf(fmaf(dn, a[5], bb1.y), 0.f);
    float r6 = fmaxf(fmaf(dn, a[6], bb1.z), 0.f);
    float r7 = fmaxf(fmaf(dn, a[7], bb1.w), 0.f);
    if (BF16OUT) {
        uint4 o;
        o.x = (uint32)f2bf(r0) | ((uint32)f2bf(r1) << 16);
        o.y = (uint32)f2bf(r2) | ((uint32)f2bf(r3) << 16);
        o.z = (uint32)f2bf(r4) | ((uint32)f2bf(r5) << 16);
        o.w = (uint32)f2bf(r6) | ((uint32)f2bf(r7) << 16);
        ((uint4*)Hout)[(size_t)n * 16 + li] = o;
    } else {
        float4* H4 = (float4*)Hout;
        float4 o0; o0.x = r0; o0.y = r1; o0.z = r2; o0.w = r3;
        float4 o1; o1.x = r4; o1.y = r5; o1.z = r6; o1.w = r7;
        H4[(size_t)n * 32 + li * 2]     = o0;
        H4[(size_t)n * 32 + li * 2 + 1] = o1;
    }
}

extern "C" void kernel_launch(void* const* d_in, const int* in_sizes, int n_in,
                              void* d_out, int out_size, void* d_ws, size_t ws_size,
                              hipStream_t stream) {
    const float* x  = (const float*)d_in[0];
    const int*   ei = (const int*)d_in[1];   // int32 per harness contract
    const float* W1 = (const float*)d_in[2];
    const float* b1 = (const float*)d_in[3];
    const float* W2 = (const float*)d_in[4];
    const float* b2 = (const float*)d_in[5];
    float* out = (float*)d_out;

    char* ws = (char*)d_ws;
    size_t off = 0;
    auto alloc = [&](size_t bytes) -> void* {
        void* p = ws + off;
        off += (bytes + 255) & ~(size_t)255;
        return p;
    };
    int*    histM    = (int*)alloc((size_t)LHM * 4);
    int*    base     = (int*)alloc((size_t)LHM * 4);
    int*    bsum     = (int*)alloc((size_t)NSB * 4);
    int*    rowstart = (int*)alloc((size_t)(N_NODES + 1) * 4);
    float*  dis      = (float*)alloc((size_t)N_NODES * 4);
    uint32* edgeTmp  = (uint32*)alloc((size_t)N_EDGES * 4);
    ushort* e16      = (ushort*)alloc((size_t)N_EDGES * 2);
    ushort* Hb       = (ushort*)alloc((size_t)N_NODES * D * 2);
    ushort* HO1      = (ushort*)alloc((size_t)N_NODES * D * 2);   // layer-1 out bf16
    ushort* Hb2      = (ushort*)alloc((size_t)N_NODES * D * 2);
    ushort* W1t      = (ushort*)alloc((size_t)D * D * 2);
    ushort* W2t      = (ushort*)alloc((size_t)D * D * 2);

    const int* src = ei;             // edge_index[0]
    const int* dst = ei + N_EDGES;   // edge_index[1]

    phaseA_kernel<<<NB + 2, 256, 0, stream>>>(dst, histM, W1, W2, W1t, W2t);
    scan1g<<<NSB, 256, 0, stream>>>(histM, base, bsum);
    scan23g<<<NSB, 256, 0, stream>>>(base, bsum);
    phaseC_kernel<<<NB, 256, 0, stream>>>(src, dst, base, edgeTmp);
    phaseDG_kernel<<<NBKT, 256, 0, stream>>>(edgeTmp, base, rowstart, dis, e16,
                                             x, W1t, Hb);
    aggr_kernel<true><<<PB, 256, 0, stream>>>((const uint4*)Hb, dis, rowstart,
                                              e16, b1, HO1);
    gemm_mfma<<<GB, 256, 0, stream>>>(HO1, W2t, dis, Hb2);
    aggr_kernel<false><<<PB, 256, 0, stream>>>((const uint4*)Hb2, dis, rowstart,
                                               e16, b2, out);
}